// Round 1
// baseline (65.442 us; speedup 1.0000x reference)
//
#include <hip/hip_runtime.h>

#define NEG (-1e6f)

static constexpr int B = 32, Q = 64, K = 512, H = 64, V = 64;
static constexpr float C2LE = 2.8853900817779268f;   // 2*log2(e)
static constexpr float L2E  = 1.4426950408889634f;   // log2(e)

__device__ __forceinline__ float fexp2(float x) { return __builtin_amdgcn_exp2f(x); }
__device__ __forceinline__ float frcp(float x)  { return __builtin_amdgcn_rcpf(x); }

// ---- projections: rows [0, B*Q) -> qp, rows [B*Q, B*Q+B*K) -> kp.
// Both outputs pre-scaled by 2*log2(e) so the score loop is exp2(qs+ks) = e^{2(q+k)}.
__global__ __launch_bounds__(256) void proj_kernel(
    const float* __restrict__ queries, const float* __restrict__ keys,
    const float* __restrict__ Wq, const float* __restrict__ Wk,
    float* __restrict__ qp, float* __restrict__ kp)
{
  __shared__ float xrow[4][H];
  const int sub = threadIdx.x >> 6, h = threadIdx.x & 63;
  const int row = blockIdx.x * 4 + sub;
  const float* src; const float* W; float* dst;
  if (row < B*Q) { src = queries + (size_t)row*H; W = Wq; dst = qp + (size_t)row*H; }
  else { const int rr = row - B*Q; src = keys + (size_t)rr*H; W = Wk; dst = kp + (size_t)rr*H; }
  xrow[sub][h] = src[h];
  __syncthreads();
  float acc = 0.f;
  #pragma unroll
  for (int d = 0; d < H; ++d) acc = fmaf(xrow[sub][d], W[d*H + h], acc);
  dst[h] = acc * C2LE;
}

// ---- main: one block per (b, 4 queries). 256 threads = 4 waves.
__global__ __launch_bounds__(256) void attn_kernel(
    const float* __restrict__ qp, const float* __restrict__ kp,
    const float* __restrict__ values, const int* __restrict__ vlens,
    const float* __restrict__ wv, float* __restrict__ out)
{
  __shared__ float2 q2[4][H];        // .x = scaled q, .y = -2*wv[h]
  __shared__ float4 p4[K];           // per-key scores, then probs, for the 4 queries
  __shared__ float part[4][4][V];    // [wave][qi][v] PV partials
  __shared__ float inv_sum[4];
  __shared__ float swv_sh;

  const int tid = threadIdx.x, lane = tid & 63, wave = tid >> 6;
  const int b = blockIdx.x >> 4, q0 = (blockIdx.x & 15) << 2;
  const int vlen = vlens[b];

  // stage q2 (wave w -> query row w); wave 0 also computes Swv = sum(wv)
  {
    const float w2 = -2.f * wv[lane];
    const float qs = qp[((size_t)b*Q + q0 + wave)*H + lane];
    q2[wave][lane] = make_float2(qs, w2);
  }
  if (wave == 0) {
    float x = wv[lane];
    #pragma unroll
    for (int off = 32; off; off >>= 1) x += __shfl_xor(x, off, 64);
    if (lane == 0) swv_sh = x;
  }
  __syncthreads();
  const float Swv = swv_sh;

  // ---- score phase: 2 keys per thread, key row held in 64 VGPRs, reused for 4 queries.
  // wv_h * tanh(x) = wv_h - 2*wv_h / (1 + e^{2x});  e^{2x} = exp2(qs + ks) (pre-scaled).
  const float* kbase = kp + (size_t)b*K*H;
  #pragma unroll
  for (int kk = 0; kk < 2; ++kk) {
    const int k = tid + kk*256;
    float kr[H];
    {
      const float4* s4 = (const float4*)(kbase + (size_t)k*H);
      float4* d4 = (float4*)kr;
      #pragma unroll
      for (int i = 0; i < 16; ++i) d4[i] = s4[i];
    }
    float sc[4];
    #pragma unroll
    for (int qi = 0; qi < 4; ++qi) {
      float a0 = 0.f, a1 = 0.f;
      #pragma unroll
      for (int h = 0; h < H; h += 2) {
        const float2 t0 = q2[qi][h];
        const float2 t1 = q2[qi][h+1];
        a0 = fmaf(t0.y, frcp(1.f + fexp2(t0.x + kr[h  ])), a0);
        a1 = fmaf(t1.y, frcp(1.f + fexp2(t1.x + kr[h+1])), a1);
      }
      sc[qi] = (k < vlen) ? (Swv + a0 + a1) : NEG;
    }
    p4[k] = make_float4(sc[0], sc[1], sc[2], sc[3]);
  }
  __syncthreads();

  // ---- masked softmax over K: wave w owns query w
  {
    float* pf = (float*)p4;
    const int qi = wave;
    float s[8]; float m = NEG;
    #pragma unroll
    for (int j = 0; j < 8; ++j) { s[j] = pf[(lane + j*64)*4 + qi]; m = fmaxf(m, s[j]); }
    #pragma unroll
    for (int off = 32; off; off >>= 1) m = fmaxf(m, __shfl_xor(m, off, 64));
    float sum = 0.f;
    #pragma unroll
    for (int j = 0; j < 8; ++j) {
      const float p = fexp2((s[j] - m) * L2E);
      pf[(lane + j*64)*4 + qi] = p;
      sum += p;
    }
    #pragma unroll
    for (int off = 32; off; off >>= 1) sum += __shfl_xor(sum, off, 64);
    if (lane == 0) inv_sum[qi] = 1.f / sum;
  }
  __syncthreads();

  // ---- PV: wave w covers keys [w*128, w*128+128), lane = v; one pass over values[b].
  {
    const float* vb = values + (size_t)b*K*V + lane;
    float a0 = 0.f, a1 = 0.f, a2 = 0.f, a3 = 0.f;
    const int kb = wave*128;
    #pragma unroll 4
    for (int k = kb; k < kb + 128; ++k) {
      const float4 p = p4[k];
      const float vv = vb[(size_t)k*V];
      a0 = fmaf(p.x, vv, a0); a1 = fmaf(p.y, vv, a1);
      a2 = fmaf(p.z, vv, a2); a3 = fmaf(p.w, vv, a3);
    }
    part[wave][0][lane] = a0; part[wave][1][lane] = a1;
    part[wave][2][lane] = a2; part[wave][3][lane] = a3;
  }
  __syncthreads();

  // ---- cross-wave reduce + normalize + write: wave w owns query w, lane = v
  {
    const int qi = wave;
    const float o = (part[0][qi][lane] + part[1][qi][lane] +
                     part[2][qi][lane] + part[3][qi][lane]) * inv_sum[qi];
    out[((size_t)b*Q + q0 + qi)*V + lane] = o;
  }
}

extern "C" void kernel_launch(void* const* d_in, const int* in_sizes, int n_in,
                              void* d_out, int out_size, void* d_ws, size_t ws_size,
                              hipStream_t stream) {
  const float* queries = (const float*)d_in[0];
  const float* keys    = (const float*)d_in[1];
  const float* values  = (const float*)d_in[2];
  const int*   vlens   = (const int*)d_in[3];
  const float* Wq      = (const float*)d_in[4];
  const float* Wk      = (const float*)d_in[5];
  const float* wv      = (const float*)d_in[6];
  float* out = (float*)d_out;

  float* qp = (float*)d_ws;                 // B*Q*H floats (scaled)
  float* kp = qp + (size_t)B*Q*H;           // B*K*H floats (scaled)

  proj_kernel<<<(B*Q + B*K) / 4, 256, 0, stream>>>(queries, keys, Wq, Wk, qp, kp);
  attn_kernel<<<B*(Q/4), 256, 0, stream>>>(qp, kp, values, vlens, wv, out);
}

// Round 2
// 48.229 us; speedup vs baseline: 1.3569x; 1.3569x over previous
//
#include <hip/hip_runtime.h>

#define NEG (-1e6f)

static constexpr int B = 32, Q = 64, K = 512, H = 64, V = 64;
static constexpr float C2LE = 2.8853900817779268f;   // 2*log2(e)
static constexpr float L2E  = 1.4426950408889634f;   // log2(e)

__device__ __forceinline__ float fexp2(float x) { return __builtin_amdgcn_exp2f(x); }
__device__ __forceinline__ float frcp(float x)  { return __builtin_amdgcn_rcpf(x); }

// ---- projections: 32 rows per block, W column held in 64 VGPRs (reused 8x/wave),
// x rows via scalar loads (row pointer is wave-uniform). Outputs pre-scaled by
// 2*log2(e) so the score loop computes exp2(qs+ks) = e^{2(q+k)}.
__global__ __launch_bounds__(256) void proj_kernel(
    const float* __restrict__ queries, const float* __restrict__ keys,
    const float* __restrict__ Wq, const float* __restrict__ Wk,
    const float* __restrict__ wv,
    float* __restrict__ qp, float* __restrict__ kp, float* __restrict__ w2)
{
  const int lane = threadIdx.x & 63;
  const int wave = __builtin_amdgcn_readfirstlane(threadIdx.x >> 6);
  const int row0 = blockIdx.x * 32;
  const float* W; const float* x0; float* dst; int rbase;
  if (row0 < B*Q) { W = Wq; x0 = queries; dst = qp; rbase = row0; }
  else            { W = Wk; x0 = keys;    dst = kp; rbase = row0 - B*Q; }
  if (blockIdx.x == 0 && wave == 0) w2[lane] = -2.f * wv[lane];

  float wcol[H];
  #pragma unroll
  for (int d = 0; d < H; ++d) wcol[d] = W[d*H + lane];   // coalesced, L1-resident

  #pragma unroll
  for (int r = 0; r < 8; ++r) {
    const int row = rbase + r*4 + wave;                  // wave-uniform
    const float* x = x0 + (size_t)row*H;                 // -> s_load
    float acc = 0.f;
    #pragma unroll
    for (int d = 0; d < H; ++d) acc = fmaf(x[d], wcol[d], acc);
    dst[(size_t)row*H + lane] = acc * C2LE;
  }
}

// ---- fused attention: one block per (b, 2 queries). 256 threads = 4 waves.
// Score phase: thread = key, q & w2 on the SCALAR pipe (wave-uniform loads),
// k-row chunked 16 floats in VGPRs. No LDS in the hot loop.
// wv_h*tanh(x) = wv_h - 2*wv_h/(1+e^{2x}); constant sum(wv) dropped
// (softmax is shift-invariant).
__global__ __launch_bounds__(256) void attn_kernel(
    const float* __restrict__ qp, const float* __restrict__ kp,
    const float* __restrict__ values, const int* __restrict__ vlens,
    const float* __restrict__ w2, float* __restrict__ out)
{
  __shared__ float p[2][K];          // scores -> probs, [query][key], 4KB
  __shared__ float part[4][2][V];    // PV partials [wave][query][v], 2KB
  __shared__ float red[2][2][2];     // [query][half][max,sum]

  const int tid = threadIdx.x;
  const int lane = tid & 63;
  const int wave = __builtin_amdgcn_readfirstlane(tid >> 6);
  const int b = blockIdx.x >> 5, q0 = (blockIdx.x & 31) << 1;
  const int vlen = vlens[b];
  const float* qbase = qp + ((size_t)b*Q + q0)*H;   // 2 query rows, uniform
  const float* kbase = kp + (size_t)b*K*H;

  // ---- phase 1: scores for 2 queries x 512 keys (2 keys/thread)
  #pragma unroll
  for (int kk = 0; kk < 2; ++kk) {
    const int k = kk*256 + tid;
    const float* krow = kbase + (size_t)k*H;
    float acc0 = 0.f, acc1 = 0.f;
    #pragma unroll
    for (int hc = 0; hc < H; hc += 16) {
      float kr[16];
      *(float4*)(kr+ 0) = *(const float4*)(krow+hc+ 0);
      *(float4*)(kr+ 4) = *(const float4*)(krow+hc+ 4);
      *(float4*)(kr+ 8) = *(const float4*)(krow+hc+ 8);
      *(float4*)(kr+12) = *(const float4*)(krow+hc+12);
      #pragma unroll
      for (int j = 0; j < 16; ++j) {
        const float w  = w2[hc+j];              // uniform -> SGPR
        const float e0 = fexp2(qbase[    hc+j] + kr[j]);
        const float e1 = fexp2(qbase[H + hc+j] + kr[j]);
        acc0 = fmaf(w, frcp(1.f + e0), acc0);
        acc1 = fmaf(w, frcp(1.f + e1), acc1);
      }
    }
    p[0][k] = acc0;                              // stride-1 writes, no conflicts
    p[1][k] = acc1;
  }
  __syncthreads();

  // ---- phase 2: masked softmax, all 4 waves busy (wave = qi*? -> qi,half)
  const int qi = wave & 1, half = wave >> 1;
  {
    const int kb2 = half*256 + lane*4;
    float s[4];
    *(float4*)s = *(const float4*)&p[qi][kb2];   // consecutive b128, conflict-free
    float m = NEG;
    #pragma unroll
    for (int j = 0; j < 4; ++j) {
      s[j] = (kb2 + j < vlen) ? s[j] : NEG;
      m = fmaxf(m, s[j]);
    }
    #pragma unroll
    for (int off = 32; off; off >>= 1) m = fmaxf(m, __shfl_xor(m, off, 64));
    if (lane == 0) red[qi][half][0] = m;
    __syncthreads();
    m = fmaxf(red[qi][0][0], red[qi][1][0]);
    float sum = 0.f;
    #pragma unroll
    for (int j = 0; j < 4; ++j) { s[j] = fexp2((s[j] - m) * L2E); sum += s[j]; }
    *(float4*)&p[qi][kb2] = *(float4*)s;
    #pragma unroll
    for (int off = 32; off; off >>= 1) sum += __shfl_xor(sum, off, 64);
    if (lane == 0) red[qi][half][1] = sum;
    __syncthreads();
  }

  // ---- phase 3: PV. wave covers keys [wave*128, wave*128+128), lane = v.
  {
    const float* vb = values + (size_t)b*K*V + lane;
    float a0 = 0.f, a1 = 0.f;
    const int kb = wave*128;
    #pragma unroll 2
    for (int k4 = kb; k4 < kb + 128; k4 += 4) {
      const float4 p0 = *(const float4*)&p[0][k4];   // broadcast b128, free
      const float4 p1 = *(const float4*)&p[1][k4];
      const float v0 = vb[(size_t)(k4+0)*V];
      const float v1 = vb[(size_t)(k4+1)*V];
      const float v2 = vb[(size_t)(k4+2)*V];
      const float v3 = vb[(size_t)(k4+3)*V];
      a0 = fmaf(p0.x,v0, fmaf(p0.y,v1, fmaf(p0.z,v2, fmaf(p0.w,v3, a0))));
      a1 = fmaf(p1.x,v0, fmaf(p1.y,v1, fmaf(p1.z,v2, fmaf(p1.w,v3, a1))));
    }
    part[wave][0][lane] = a0;
    part[wave][1][lane] = a1;
  }
  __syncthreads();

  // ---- phase 4: cross-wave reduce + normalize + write (waves 0,1)
  if (wave < 2) {
    const float inv = frcp(red[wave][0][1] + red[wave][1][1]);
    const float o = (part[0][wave][lane] + part[1][wave][lane] +
                     part[2][wave][lane] + part[3][wave][lane]) * inv;
    out[((size_t)b*Q + q0 + wave)*V + lane] = o;
  }
}

extern "C" void kernel_launch(void* const* d_in, const int* in_sizes, int n_in,
                              void* d_out, int out_size, void* d_ws, size_t ws_size,
                              hipStream_t stream) {
  const float* queries = (const float*)d_in[0];
  const float* keys    = (const float*)d_in[1];
  const float* values  = (const float*)d_in[2];
  const int*   vlens   = (const int*)d_in[3];
  const float* Wq      = (const float*)d_in[4];
  const float* Wk      = (const float*)d_in[5];
  const float* wv      = (const float*)d_in[6];
  float* out = (float*)d_out;

  float* qp = (float*)d_ws;                 // B*Q*H floats (scaled)
  float* kp = qp + (size_t)B*Q*H;           // B*K*H floats (scaled)
  float* w2 = kp + (size_t)B*K*H;           // H floats (-2*wv)

  proj_kernel<<<(B*Q + B*K) / 32, 256, 0, stream>>>(queries, keys, Wq, Wk, wv, qp, kp, w2);
  attn_kernel<<<B*(Q/2), 256, 0, stream>>>(qp, kp, values, vlens, w2, out);
}

// Round 3
// 32.629 us; speedup vs baseline: 2.0056x; 1.4781x over previous
//
#include <hip/hip_runtime.h>

#define NEG (-1e6f)

static constexpr int B = 32, Q = 64, K = 512, H = 64, V = 64;
static constexpr float C2LE = 2.8853900817779268f;   // 2*log2(e)
static constexpr float L2E  = 1.4426950408889634f;   // log2(e)

__device__ __forceinline__ float fexp2(float x) { return __builtin_amdgcn_exp2f(x); }
__device__ __forceinline__ float frcp(float x)  { return __builtin_amdgcn_rcpf(x); }

// ---- projections + exponentials.
// Query rows  -> qAR[row*H+h] = { -2*wv_h * e^{-2q_h},  e^{-2q_h} }
// Key rows    -> Ek[row*H+h]  =   e^{2k_h}
// Then  wv_h*tanh(q+k) = wv_h + A_h * rcp(Rq_h + Ek_h)   (constant sum(wv)
// dropped later: softmax is shift-invariant). Proj values clamped to +-15
// (tanh is fully saturated there) so the exponentials can never overflow.
__global__ __launch_bounds__(256) void proj_kernel(
    const float* __restrict__ queries, const float* __restrict__ keys,
    const float* __restrict__ Wq, const float* __restrict__ Wk,
    const float* __restrict__ wv,
    float2* __restrict__ qAR, float* __restrict__ Ek)
{
  const int lane = threadIdx.x & 63;
  const int wave = __builtin_amdgcn_readfirstlane(threadIdx.x >> 6);
  const int row0 = blockIdx.x * 32;
  const bool isQ = row0 < B*Q;                          // block-uniform
  const float* W  = isQ ? Wq : Wk;
  const float* x0 = isQ ? queries : keys;
  const int rbase = isQ ? row0 : row0 - B*Q;

  float wcol[H];
  #pragma unroll
  for (int d = 0; d < H; ++d) wcol[d] = W[d*H + lane];  // coalesced, L1/L2-warm
  const float w2l = -2.f * wv[lane];

  #pragma unroll
  for (int r = 0; r < 8; ++r) {
    const int row = rbase + r*4 + wave;                 // wave-uniform
    const float* x = x0 + (size_t)row*H;                // -> s_load
    float acc = 0.f;
    #pragma unroll
    for (int d = 0; d < H; ++d) acc = fmaf(x[d], wcol[d], acc);
    acc = fminf(15.f, fmaxf(-15.f, acc));
    if (isQ) {
      const float rq = fexp2(-C2LE * acc);
      qAR[(size_t)row*H + lane] = make_float2(w2l * rq, rq);
    } else {
      Ek[(size_t)row*H + lane] = fexp2(C2LE * acc);
    }
  }
}

// ---- fused attention: one block per (b, 4 queries). 512 threads = 8 waves.
// Score phase: thread = key; per element just  add + rcp + fma  (1 trans).
// A/Rq are wave-uniform (scalar pipe); Ek chunk lives in VGPRs; no LDS in
// the hot loop.
__global__ __launch_bounds__(512) void attn_kernel(
    const float2* __restrict__ qAR, const float* __restrict__ Ek,
    const float* __restrict__ values, const int* __restrict__ vlens,
    float* __restrict__ out)
{
  __shared__ float p[4][K];          // scores -> probs, 8KB
  __shared__ float part[8][4][V];    // PV partials [wave][query][v], 8KB
  __shared__ float red[4][2][2];     // [query][half][max,sum]

  const int tid = threadIdx.x, lane = tid & 63;
  const int wave = __builtin_amdgcn_readfirstlane(tid >> 6);
  const int b = blockIdx.x >> 4, q0 = (blockIdx.x & 15) << 2;
  const int vlen = vlens[b];
  const float2* ar0 = qAR + ((size_t)b*Q + q0)*H;      // 4 query rows, uniform

  // ---- phase 1: scores for 4 queries x 512 keys (1 key/thread)
  {
    const float* ekrow = Ek + ((size_t)b*K + tid)*H;
    float acc0 = 0.f, acc1 = 0.f, acc2 = 0.f, acc3 = 0.f;
    #pragma unroll
    for (int hc = 0; hc < H; hc += 8) {
      float ek[8];
      *(float4*)(ek+0) = *(const float4*)(ekrow+hc+0);
      *(float4*)(ek+4) = *(const float4*)(ekrow+hc+4);
      #pragma unroll
      for (int j = 0; j < 8; ++j) {
        const float2 a0 = ar0[0*H + hc + j];           // uniform -> SGPR
        const float2 a1 = ar0[1*H + hc + j];
        const float2 a2 = ar0[2*H + hc + j];
        const float2 a3 = ar0[3*H + hc + j];
        acc0 = fmaf(a0.x, frcp(a0.y + ek[j]), acc0);
        acc1 = fmaf(a1.x, frcp(a1.y + ek[j]), acc1);
        acc2 = fmaf(a2.x, frcp(a2.y + ek[j]), acc2);
        acc3 = fmaf(a3.x, frcp(a3.y + ek[j]), acc3);
      }
    }
    p[0][tid] = acc0; p[1][tid] = acc1; p[2][tid] = acc2; p[3][tid] = acc3;
  }
  __syncthreads();

  // ---- phase 2: masked softmax; wave = (query, half of K). 8 waves busy.
  const int qi = wave & 3, half = wave >> 2;
  {
    const int kb2 = half*256 + lane*4;
    float s[4];
    *(float4*)s = *(const float4*)&p[qi][kb2];
    float m = NEG;
    #pragma unroll
    for (int j = 0; j < 4; ++j) {
      s[j] = (kb2 + j < vlen) ? s[j] : NEG;
      m = fmaxf(m, s[j]);
    }
    #pragma unroll
    for (int off = 32; off; off >>= 1) m = fmaxf(m, __shfl_xor(m, off, 64));
    if (lane == 0) red[qi][half][0] = m;
    __syncthreads();
    m = fmaxf(red[qi][0][0], red[qi][1][0]);
    float sum = 0.f;
    #pragma unroll
    for (int j = 0; j < 4; ++j) { s[j] = fexp2((s[j] - m) * L2E); sum += s[j]; }
    *(float4*)&p[qi][kb2] = *(float4*)s;
    #pragma unroll
    for (int off = 32; off; off >>= 1) sum += __shfl_xor(sum, off, 64);
    if (lane == 0) red[qi][half][1] = sum;
    __syncthreads();
  }

  // ---- phase 3: PV. wave covers keys [wave*64, wave*64+64), lane = v.
  {
    const int kb = wave*64;
    const float* vb = values + ((size_t)b*K + kb)*V + lane;
    float a0 = 0.f, a1 = 0.f, a2 = 0.f, a3 = 0.f;
    #pragma unroll 4
    for (int k = 0; k < 64; k += 4) {
      const float4 p0 = *(const float4*)&p[0][kb+k];   // uniform addr: broadcast
      const float4 p1 = *(const float4*)&p[1][kb+k];
      const float4 p2 = *(const float4*)&p[2][kb+k];
      const float4 p3 = *(const float4*)&p[3][kb+k];
      const float v0 = vb[(size_t)(k+0)*V];
      const float v1 = vb[(size_t)(k+1)*V];
      const float v2 = vb[(size_t)(k+2)*V];
      const float v3 = vb[(size_t)(k+3)*V];
      a0 = fmaf(p0.x,v0, fmaf(p0.y,v1, fmaf(p0.z,v2, fmaf(p0.w,v3, a0))));
      a1 = fmaf(p1.x,v0, fmaf(p1.y,v1, fmaf(p1.z,v2, fmaf(p1.w,v3, a1))));
      a2 = fmaf(p2.x,v0, fmaf(p2.y,v1, fmaf(p2.z,v2, fmaf(p2.w,v3, a2))));
      a3 = fmaf(p3.x,v0, fmaf(p3.y,v1, fmaf(p3.z,v2, fmaf(p3.w,v3, a3))));
    }
    part[wave][0][lane] = a0; part[wave][1][lane] = a1;
    part[wave][2][lane] = a2; part[wave][3][lane] = a3;
  }
  __syncthreads();

  // ---- phase 4: cross-wave reduce + normalize + write (waves 0..3)
  if (wave < 4) {
    const float inv = frcp(red[wave][0][1] + red[wave][1][1]);
    float o = 0.f;
    #pragma unroll
    for (int w = 0; w < 8; ++w) o += part[w][wave][lane];
    out[((size_t)b*Q + q0 + wave)*V + lane] = o * inv;
  }
}

extern "C" void kernel_launch(void* const* d_in, const int* in_sizes, int n_in,
                              void* d_out, int out_size, void* d_ws, size_t ws_size,
                              hipStream_t stream) {
  const float* queries = (const float*)d_in[0];
  const float* keys    = (const float*)d_in[1];
  const float* values  = (const float*)d_in[2];
  const int*   vlens   = (const int*)d_in[3];
  const float* Wq      = (const float*)d_in[4];
  const float* Wk      = (const float*)d_in[5];
  const float* wv      = (const float*)d_in[6];
  float* out = (float*)d_out;

  float2* qAR = (float2*)d_ws;                       // B*Q*H float2 (1MB)
  float*  Ek  = (float*)(qAR + (size_t)B*Q*H);       // B*K*H floats (4MB)

  proj_kernel<<<(B*Q + B*K) / 32, 256, 0, stream>>>(queries, keys, Wq, Wk, wv, qAR, Ek);
  attn_kernel<<<B*(Q/4), 512, 0, stream>>>(qAR, Ek, values, vlens, out);
}

// Round 4
// 29.115 us; speedup vs baseline: 2.2477x; 1.1207x over previous
//
#include <hip/hip_runtime.h>

#define NEG (-1e6f)

static constexpr int B = 32, Q = 64, K = 512, H = 64, V = 64;
static constexpr float C2LE = 2.8853900817779268f;   // 2*log2(e)
static constexpr float L2E  = 1.4426950408889634f;   // log2(e)

typedef __attribute__((ext_vector_type(8))) short bf16x8;
typedef __attribute__((ext_vector_type(4))) float f32x4;

__device__ __forceinline__ float fexp2(float x) { return __builtin_amdgcn_exp2f(x); }
__device__ __forceinline__ float frcp(float x)  { return __builtin_amdgcn_rcpf(x); }

__device__ __forceinline__ short f2bf(float f) {  // RNE f32 -> bf16
  union { float f; unsigned u; } v; v.f = f;
  unsigned r = v.u + 0x7fffu + ((v.u >> 16) & 1u);
  return (short)(r >> 16);
}

// ---- MFMA projections + fused exponentials.
// Rows 0..2047 = queries -> qAR[row*H+h] = { -2*wv_h*e^{-2q}, e^{-2q} }
// Rows 2048..18431 = keys -> Ek[(row-2048)*H+h] = e^{2k}
// wv_h*tanh(q+k) = wv_h + A*rcp(R+E); constant sum(wv) dropped (softmax shift-inv).
// Clamp +-15 before exp (tanh saturated) so nothing overflows.
// MFMA 16x16x32 bf16 layout (m89/m91-verified): A: row=l&15,k=(l>>4)*8+j;
// B: col=l&15, same k; C/D: col=l&15, row=(l>>4)*4+reg.
__global__ __launch_bounds__(256) void proj_kernel(
    const float* __restrict__ queries, const float* __restrict__ keys,
    const float* __restrict__ Wq, const float* __restrict__ Wk,
    const float* __restrict__ wv,
    float2* __restrict__ qAR, float* __restrict__ Ek)
{
  __shared__ float Wl[64 * 65];                    // +1 pad: <=2-way conflicts (free)
  const int tid = threadIdx.x;
  const int lane = tid & 63;
  const int wave = __builtin_amdgcn_readfirstlane(tid >> 6);
  const int stripe0 = blockIdx.x * 4;              // 16-row stripes; 1152 total
  const bool isQ = stripe0 < 128;                  // 2048 q-rows / 16 (block-uniform)
  const float* Wsrc = isQ ? Wq : Wk;

  #pragma unroll
  for (int i = 0; i < 16; ++i) {                   // stage W (coalesced)
    const int idx = tid + i * 256;
    Wl[(idx >> 6) * 65 + (idx & 63)] = Wsrc[idx];
  }
  __syncthreads();

  const int stripe = stripe0 + wave;
  const int row0 = stripe * 16;
  const int r = lane & 15, g = lane >> 4;          // tile-row / k-group
  const float* xbase = isQ ? (queries + (size_t)row0 * H)
                           : (keys + (size_t)(row0 - 2048) * H);

  bf16x8 afr[2];
  #pragma unroll
  for (int kb = 0; kb < 2; ++kb) {                 // A frags: 8 contiguous k per lane
    const float* px = xbase + (size_t)r * H + kb * 32 + g * 8;
    const float4 x0 = *(const float4*)px;
    const float4 x1 = *(const float4*)(px + 4);
    bf16x8 a;
    a[0]=f2bf(x0.x); a[1]=f2bf(x0.y); a[2]=f2bf(x0.z); a[3]=f2bf(x0.w);
    a[4]=f2bf(x1.x); a[5]=f2bf(x1.y); a[6]=f2bf(x1.z); a[7]=f2bf(x1.w);
    afr[kb] = a;
  }

  #pragma unroll
  for (int c = 0; c < 4; ++c) {                    // 4 col-tiles of 16
    const int col = c * 16 + r;
    f32x4 acc = {0.f, 0.f, 0.f, 0.f};
    #pragma unroll
    for (int kb = 0; kb < 2; ++kb) {
      bf16x8 bfr;
      #pragma unroll
      for (int j = 0; j < 8; ++j)
        bfr[j] = f2bf(Wl[(kb*32 + g*8 + j) * 65 + col]);
      acc = __builtin_amdgcn_mfma_f32_16x16x32_bf16(afr[kb], bfr, acc, 0, 0, 0);
    }
    const float wvv = wv[col];
    #pragma unroll
    for (int rr = 0; rr < 4; ++rr) {
      const int row = row0 + g * 4 + rr;           // C: row=(l>>4)*4+reg, col=l&15
      const float s = fminf(15.f, fmaxf(-15.f, acc[rr])) * C2LE;
      if (isQ) {
        const float rq = fexp2(-s);
        qAR[(size_t)row * H + col] = make_float2(-2.f * wvv * rq, rq);
      } else {
        Ek[(size_t)(row - 2048) * H + col] = fexp2(s);
      }
    }
  }
}

// ---- fused attention: one block per (b, 4 queries). 1024 threads = 16 waves.
// Score phase h-split: thread = (key, h-half); per element add+rcp+fma (1 trans).
// q-operands wave-uniform -> scalar pipe. 2 blocks/CU -> 8 waves/SIMD.
__global__ __launch_bounds__(1024, 8) void attn_kernel(
    const float2* __restrict__ qAR, const float* __restrict__ Ek,
    const float* __restrict__ values, const int* __restrict__ vlens,
    float* __restrict__ out)
{
  __shared__ float pp[2][4][K];      // 16KB: [half][query][key] partials -> probs in pp[0]
  __shared__ float part[16][4][V];   // 16KB: PV partials
  __shared__ float red[4][4][2];     // [query][quarter][max,sum]

  const int tid = threadIdx.x, lane = tid & 63;
  const int wave = __builtin_amdgcn_readfirstlane(tid >> 6);
  const int b = blockIdx.x >> 4, q0 = (blockIdx.x & 15) << 2;
  const int vlen = vlens[b];
  const float2* ar0 = qAR + ((size_t)b * Q + q0) * H;

  // ---- phase 1: scores, thread = (key, h-half), 32 h each, 4 queries
  {
    const int key = tid & 511;
    const int half = __builtin_amdgcn_readfirstlane(tid >> 9);  // wave-uniform
    const float* ekrow = Ek + ((size_t)b * K + key) * H + half * 32;
    const float2* arh = ar0 + half * 32;
    float a0 = 0.f, a1 = 0.f, a2 = 0.f, a3 = 0.f;
    #pragma unroll
    for (int hc = 0; hc < 32; hc += 8) {
      float ek[8];
      *(float4*)(ek + 0) = *(const float4*)(ekrow + hc + 0);
      *(float4*)(ek + 4) = *(const float4*)(ekrow + hc + 4);
      #pragma unroll
      for (int j = 0; j < 8; ++j) {
        const float2 v0 = arh[0*H + hc + j];       // uniform -> s_load
        const float2 v1 = arh[1*H + hc + j];
        const float2 v2 = arh[2*H + hc + j];
        const float2 v3 = arh[3*H + hc + j];
        a0 = fmaf(v0.x, frcp(v0.y + ek[j]), a0);
        a1 = fmaf(v1.x, frcp(v1.y + ek[j]), a1);
        a2 = fmaf(v2.x, frcp(v2.y + ek[j]), a2);
        a3 = fmaf(v3.x, frcp(v3.y + ek[j]), a3);
      }
    }
    pp[half][0][key] = a0; pp[half][1][key] = a1;
    pp[half][2][key] = a2; pp[half][3][key] = a3;
  }
  __syncthreads();

  // ---- phase 2: combine halves + masked softmax; wave = (query, quarter)
  const int qi = wave & 3, quarter = wave >> 2;
  const int kq = quarter * 128 + lane * 2;
  float2 s;
  {
    const float2 u0 = *(const float2*)&pp[0][qi][kq];
    const float2 u1 = *(const float2*)&pp[1][qi][kq];
    s.x = (kq     < vlen) ? u0.x + u1.x : NEG;
    s.y = (kq + 1 < vlen) ? u0.y + u1.y : NEG;
    float m = fmaxf(s.x, s.y);
    #pragma unroll
    for (int off = 32; off; off >>= 1) m = fmaxf(m, __shfl_xor(m, off, 64));
    if (lane == 0) red[qi][quarter][0] = m;
  }
  __syncthreads();
  {
    const float m = fmaxf(fmaxf(red[qi][0][0], red[qi][1][0]),
                          fmaxf(red[qi][2][0], red[qi][3][0]));
    s.x = fexp2((s.x - m) * L2E);
    s.y = fexp2((s.y - m) * L2E);
    *(float2*)&pp[0][qi][kq] = s;                  // probs into pp[0]
    float sum = s.x + s.y;
    #pragma unroll
    for (int off = 32; off; off >>= 1) sum += __shfl_xor(sum, off, 64);
    if (lane == 0) red[qi][quarter][1] = sum;
  }
  __syncthreads();

  // ---- phase 3: PV. wave covers keys [wave*32, wave*32+32), lane = v
  {
    const int kb = wave * 32;
    const float* vb = values + ((size_t)b * K + kb) * V + lane;
    float a0 = 0.f, a1 = 0.f, a2 = 0.f, a3 = 0.f;
    #pragma unroll
    for (int k4 = 0; k4 < 32; k4 += 4) {
      const float4 p0 = *(const float4*)&pp[0][0][kb + k4];  // uniform: broadcast
      const float4 p1 = *(const float4*)&pp[0][1][kb + k4];
      const float4 p2 = *(const float4*)&pp[0][2][kb + k4];
      const float4 p3 = *(const float4*)&pp[0][3][kb + k4];
      const float v0 = vb[(size_t)(k4 + 0) * V];
      const float v1 = vb[(size_t)(k4 + 1) * V];
      const float v2 = vb[(size_t)(k4 + 2) * V];
      const float v3 = vb[(size_t)(k4 + 3) * V];
      a0 = fmaf(p0.x,v0, fmaf(p0.y,v1, fmaf(p0.z,v2, fmaf(p0.w,v3, a0))));
      a1 = fmaf(p1.x,v0, fmaf(p1.y,v1, fmaf(p1.z,v2, fmaf(p1.w,v3, a1))));
      a2 = fmaf(p2.x,v0, fmaf(p2.y,v1, fmaf(p2.z,v2, fmaf(p2.w,v3, a2))));
      a3 = fmaf(p3.x,v0, fmaf(p3.y,v1, fmaf(p3.z,v2, fmaf(p3.w,v3, a3))));
    }
    part[wave][0][lane] = a0; part[wave][1][lane] = a1;
    part[wave][2][lane] = a2; part[wave][3][lane] = a3;
  }
  __syncthreads();

  // ---- phase 4: cross-wave reduce + normalize + write (waves 0..3)
  if (wave < 4) {
    const float inv = frcp(red[wave][0][1] + red[wave][1][1] +
                           red[wave][2][1] + red[wave][3][1]);
    float o = 0.f;
    #pragma unroll
    for (int w = 0; w < 16; ++w) o += part[w][wave][lane];
    out[((size_t)b * Q + q0 + wave) * V + lane] = o * inv;
  }
}

extern "C" void kernel_launch(void* const* d_in, const int* in_sizes, int n_in,
                              void* d_out, int out_size, void* d_ws, size_t ws_size,
                              hipStream_t stream) {
  const float* queries = (const float*)d_in[0];
  const float* keys    = (const float*)d_in[1];
  const float* values  = (const float*)d_in[2];
  const int*   vlens   = (const int*)d_in[3];
  const float* Wq      = (const float*)d_in[4];
  const float* Wk      = (const float*)d_in[5];
  const float* wv      = (const float*)d_in[6];
  float* out = (float*)d_out;

  float2* qAR = (float2*)d_ws;                       // B*Q*H float2 (1MB)
  float*  Ek  = (float*)(qAR + (size_t)B*Q*H);       // B*K*H floats (4MB)

  proj_kernel<<<(B*Q + B*K) / 64, 256, 0, stream>>>(queries, keys, Wq, Wk, wv, qAR, Ek);
  attn_kernel<<<B*(Q/4), 1024, 0, stream>>>(qAR, Ek, values, vlens, out);
}